// Round 1
// baseline (84.381 us; speedup 1.0000x reference)
//
#include <hip/hip_runtime.h>
#include <math.h>

constexpr int S_ = 4096;
constexpr int B_ = 64;
constexpr int H_ = 256;

// ws float layout:
// 0     : dW [B*H] = 16384
// 16384 : pc [B]
// 16448 : m  [B]
// 16512 : l  [B]
// 16576 : scores [B*S] = 262144

__global__ __launch_bounds__(256) void k1_prep(const float* __restrict__ d,
                                               const float* __restrict__ W_a,
                                               const float* __restrict__ W_p,
                                               const float* __restrict__ v_p,
                                               float* __restrict__ dW,
                                               float* __restrict__ pc) {
  int b = blockIdx.x;
  int h = threadIdx.x;
  float acc_a = 0.f, acc_p = 0.f;
  const float* db = d + b * H_;
  for (int k = 0; k < H_; ++k) {
    float dv = db[k];                      // uniform -> s_load
    acc_a = fmaf(dv, W_a[k * H_ + h], acc_a);
    acc_p = fmaf(dv, W_p[k * H_ + h], acc_p);
  }
  dW[b * H_ + h] = acc_a;
  float prod = tanhf(acc_p) * v_p[h];
  __shared__ float red[256];
  red[h] = prod;
  __syncthreads();
  for (int st = 128; st > 0; st >>= 1) {
    if (h < st) red[h] += red[h + st];
    __syncthreads();
  }
  if (h == 0) {
    pc[b] = (float)S_ / (1.f + expf(-red[0]));   // sigmoid * S
  }
}

// one wave per (s,b) dot product; lane i owns h-slice [4i,4i+4)
__global__ __launch_bounds__(256) void k2_scores(const float* __restrict__ e,
                                                 const float* __restrict__ dW,
                                                 float* __restrict__ scores) {
  int b = blockIdx.y;
  int wave = threadIdx.x >> 6;
  int lane = threadIdx.x & 63;
  float4 wv = *(const float4*)(dW + b * H_ + lane * 4);
  int s_base = blockIdx.x * 64 + wave * 16;
  const float* ebase = e + (size_t)b * H_ + (size_t)lane * 4;
  for (int i = 0; i < 16; ++i) {
    int s = s_base + i;
    const float4 ev = *(const float4*)(ebase + (size_t)s * (B_ * H_));
    float acc = fmaf(ev.x, wv.x, fmaf(ev.y, wv.y, fmaf(ev.z, wv.z, ev.w * wv.w)));
#pragma unroll
    for (int off = 32; off > 0; off >>= 1) acc += __shfl_xor(acc, off, 64);
    if (lane == 0) scores[b * S_ + s] = acc;
  }
}

__global__ __launch_bounds__(256) void k3a_stats(const float* __restrict__ scores,
                                                 float* __restrict__ m,
                                                 float* __restrict__ l) {
  int b = blockIdx.x;
  int t = threadIdx.x;
  const float* sc = scores + b * S_;
  float v[16];
  float lm = -INFINITY;
#pragma unroll
  for (int k = 0; k < 16; ++k) {
    v[k] = sc[t + k * 256];
    lm = fmaxf(lm, v[k]);
  }
  __shared__ float red[256];
  red[t] = lm;
  __syncthreads();
  for (int st = 128; st > 0; st >>= 1) {
    if (t < st) red[t] = fmaxf(red[t], red[t + st]);
    __syncthreads();
  }
  float mb = red[0];
  __syncthreads();
  float ls = 0.f;
#pragma unroll
  for (int k = 0; k < 16; ++k) ls += expf(v[k] - mb);
  red[t] = ls;
  __syncthreads();
  for (int st = 128; st > 0; st >>= 1) {
    if (t < st) red[t] += red[t + st];
    __syncthreads();
  }
  if (t == 0) { m[b] = mb; l[b] = red[0]; }
}

// compute w = softmax * gaussian-window, transpose [B][S]->[S][B] via LDS
__global__ __launch_bounds__(256) void k3b_weights(const float* __restrict__ scores,
                                                   const float* __restrict__ m,
                                                   const float* __restrict__ l,
                                                   const float* __restrict__ pc,
                                                   float* __restrict__ w_out) {
  __shared__ float tile[64][65];
  int t = threadIdx.x;
  int s0 = blockIdx.x * 64;
#pragma unroll
  for (int k = 0; k < 16; ++k) {
    int idx = t + k * 256;
    int b = idx >> 6;
    int sl = idx & 63;
    int s = s0 + sl;
    float a = expf(scores[b * S_ + s] - m[b]) / l[b];
    float diff = pc[b] - (float)s;
    float p = (fabsf(diff) <= 2.f) ? expf(-0.5f * diff * diff) : 0.f;
    tile[b][sl] = a * p;
  }
  __syncthreads();
#pragma unroll
  for (int k = 0; k < 16; ++k) {
    int idx = t + k * 256;
    int sl = idx >> 6;
    int b = idx & 63;
    w_out[(size_t)(s0 + sl) * B_ + b] = tile[b][sl];
  }
}

// gather <=5 window rows of e, concat with d, fused linear + ReLU
__global__ __launch_bounds__(256) void k4_out(const float* __restrict__ e,
                                              const float* __restrict__ d,
                                              const float* __restrict__ lin_w,
                                              const float* __restrict__ lin_b,
                                              const float* __restrict__ pc,
                                              const float* __restrict__ w_out,
                                              float* __restrict__ out) {
  int b = blockIdx.x;
  int h = threadIdx.x;
  float pcb = pc[b];
  int s0 = max(0, (int)ceilf(pcb - 2.f));
  int s1 = min(S_ - 1, (int)floorf(pcb + 2.f));
  float ctx = 0.f;
  for (int s = s0; s <= s1; ++s) {
    float wv = w_out[(size_t)s * B_ + b];
    ctx = fmaf(wv, e[((size_t)s * B_ + b) * H_ + h], ctx);
  }
  __shared__ float x[512];
  x[h] = ctx;
  x[256 + h] = d[b * H_ + h];
  __syncthreads();
  float acc = lin_b[h];
  const float4* lw = (const float4*)(lin_w + h * 2 * H_);
  const float4* xv = (const float4*)x;
#pragma unroll 4
  for (int k = 0; k < 128; ++k) {
    float4 a4 = lw[k];
    float4 b4 = xv[k];
    acc += a4.x * b4.x + a4.y * b4.y + a4.z * b4.z + a4.w * b4.w;
  }
  out[b * H_ + h] = fmaxf(acc, 0.f);
}

extern "C" void kernel_launch(void* const* d_in, const int* in_sizes, int n_in,
                              void* d_out, int out_size, void* d_ws, size_t ws_size,
                              hipStream_t stream) {
  const float* e     = (const float*)d_in[0];
  const float* d     = (const float*)d_in[1];
  const float* W_a   = (const float*)d_in[2];
  const float* W_p   = (const float*)d_in[3];
  const float* v_p   = (const float*)d_in[4];
  const float* lin_w = (const float*)d_in[5];
  const float* lin_b = (const float*)d_in[6];

  float* out   = (float*)d_out;        // [1,B,H] = 16384 floats
  float* w_out = out + B_ * H_;        // [S,B]   = 262144 floats

  float* ws     = (float*)d_ws;
  float* dW     = ws;
  float* pc     = ws + 16384;
  float* m      = ws + 16448;
  float* l      = ws + 16512;
  float* scores = ws + 16576;

  k1_prep<<<B_, 256, 0, stream>>>(d, W_a, W_p, v_p, dW, pc);
  k2_scores<<<dim3(S_ / 64, B_), 256, 0, stream>>>(e, dW, scores);
  k3a_stats<<<B_, 256, 0, stream>>>(scores, m, l);
  k3b_weights<<<S_ / 64, 256, 0, stream>>>(scores, m, l, pc, w_out);
  k4_out<<<B_, 256, 0, stream>>>(e, d, lin_w, lin_b, pc, w_out, out);
}

// Round 2
// 83.874 us; speedup vs baseline: 1.0061x; 1.0061x over previous
//
#include <hip/hip_runtime.h>
#include <math.h>

constexpr int S_ = 4096;
constexpr int B_ = 64;
constexpr int H_ = 256;

// ws float layout:
// 0     : dW [B*H] = 16384
// 16384 : pc [B]
// 16448 : scores [B*S] = 262144

__global__ __launch_bounds__(256) void k1_prep(const float* __restrict__ d,
                                               const float* __restrict__ W_a,
                                               const float* __restrict__ W_p,
                                               const float* __restrict__ v_p,
                                               float* __restrict__ dW,
                                               float* __restrict__ pc) {
  int b = blockIdx.x;
  int h = threadIdx.x;
  float acc_a = 0.f, acc_p = 0.f;
  const float* db = d + b * H_;
  for (int k = 0; k < H_; ++k) {
    float dv = db[k];                      // uniform -> s_load
    acc_a = fmaf(dv, W_a[k * H_ + h], acc_a);
    acc_p = fmaf(dv, W_p[k * H_ + h], acc_p);
  }
  dW[b * H_ + h] = acc_a;
  float prod = tanhf(acc_p) * v_p[h];
  __shared__ float red[256];
  red[h] = prod;
  __syncthreads();
  for (int st = 128; st > 0; st >>= 1) {
    if (h < st) red[h] += red[h + st];
    __syncthreads();
  }
  if (h == 0) {
    pc[b] = (float)S_ / (1.f + expf(-red[0]));   // sigmoid * S
  }
}

// one wave per (s,b) dot product; lane i owns h-slice [4i,4i+4)
// grid: (B_, S_/64)  -- b is the fast grid dim so concurrently-resident
// blocks cover contiguous 64KB spans of e (DRAM page locality).
// 8 float4 loads batched per chunk -> 128B in flight per wave at low VGPR.
__global__ __launch_bounds__(256) void k2_scores(const float* __restrict__ e,
                                                 const float* __restrict__ dW,
                                                 float* __restrict__ scores) {
  int b = blockIdx.x;
  int wave = threadIdx.x >> 6;
  int lane = threadIdx.x & 63;
  float4 wv = *(const float4*)(dW + b * H_ + lane * 4);
  int s_base = blockIdx.y * 64 + wave * 16;
  const float* ebase = e + (size_t)s_base * (B_ * H_) + (size_t)b * H_ + (size_t)lane * 4;
#pragma unroll 1
  for (int c = 0; c < 2; ++c) {
    float4 ev[8];
#pragma unroll
    for (int i = 0; i < 8; ++i)
      ev[i] = *(const float4*)(ebase + (size_t)(c * 8 + i) * (B_ * H_));
#pragma unroll
    for (int i = 0; i < 8; ++i) {
      float acc = fmaf(ev[i].x, wv.x, fmaf(ev[i].y, wv.y, fmaf(ev[i].z, wv.z, ev[i].w * wv.w)));
#pragma unroll
      for (int off = 32; off > 0; off >>= 1) acc += __shfl_xor(acc, off, 64);
      if (lane == 0) scores[b * S_ + s_base + c * 8 + i] = acc;
    }
  }
}

// fused: per-b softmax stats + w write (transposed) + window context + linear + ReLU
__global__ __launch_bounds__(256) void kF(const float* __restrict__ scores,
                                          const float* __restrict__ pc,
                                          const float* __restrict__ e,
                                          const float* __restrict__ d,
                                          const float* __restrict__ lin_w,
                                          const float* __restrict__ lin_b,
                                          float* __restrict__ out,
                                          float* __restrict__ w_out) {
  int b = blockIdx.x;
  int t = threadIdx.x;
  const float* sc = scores + b * S_;
  float v[16];
  float lm = -INFINITY;
#pragma unroll
  for (int k = 0; k < 16; ++k) {
    v[k] = sc[t + k * 256];
    lm = fmaxf(lm, v[k]);
  }
  __shared__ float red[256];
  red[t] = lm;
  __syncthreads();
  for (int st = 128; st > 0; st >>= 1) {
    if (t < st) red[t] = fmaxf(red[t], red[t + st]);
    __syncthreads();
  }
  float mb = red[0];
  __syncthreads();
  float ls = 0.f;
#pragma unroll
  for (int k = 0; k < 16; ++k) ls += expf(v[k] - mb);
  red[t] = ls;
  __syncthreads();
  for (int st = 128; st > 0; st >>= 1) {
    if (t < st) red[t] += red[t + st];
    __syncthreads();
  }
  float inv_l = 1.f / red[0];
  float pcb = pc[b];
  // w = softmax * gaussian-window, write transposed [S][B] (strided 4B, 1MB total)
#pragma unroll
  for (int k = 0; k < 16; ++k) {
    int s = t + k * 256;
    float diff = pcb - (float)s;
    float p = (fabsf(diff) <= 2.f) ? expf(-0.5f * diff * diff) : 0.f;
    w_out[(size_t)s * B_ + b] = expf(v[k] - mb) * inv_l * p;
  }
  // context: gather the <=5 window rows of e (thread t = channel h)
  int s0 = max(0, (int)ceilf(pcb - 2.f));
  int s1 = min(S_ - 1, (int)floorf(pcb + 2.f));
  float ctx = 0.f;
  for (int s = s0; s <= s1; ++s) {
    float diff = pcb - (float)s;
    float wv = expf(sc[s] - mb) * inv_l * expf(-0.5f * diff * diff);
    ctx = fmaf(wv, e[((size_t)s * B_ + b) * H_ + t], ctx);
  }
  __shared__ float x[512];
  x[t] = ctx;
  x[256 + t] = d[b * H_ + t];
  __syncthreads();
  float acc = lin_b[t];
  const float4* lw = (const float4*)(lin_w + t * 2 * H_);
  const float4* xv = (const float4*)x;
#pragma unroll 4
  for (int k = 0; k < 128; ++k) {
    float4 a4 = lw[k];
    float4 b4 = xv[k];
    acc += a4.x * b4.x + a4.y * b4.y + a4.z * b4.z + a4.w * b4.w;
  }
  out[b * H_ + t] = fmaxf(acc, 0.f);
}

extern "C" void kernel_launch(void* const* d_in, const int* in_sizes, int n_in,
                              void* d_out, int out_size, void* d_ws, size_t ws_size,
                              hipStream_t stream) {
  const float* e     = (const float*)d_in[0];
  const float* d     = (const float*)d_in[1];
  const float* W_a   = (const float*)d_in[2];
  const float* W_p   = (const float*)d_in[3];
  const float* v_p   = (const float*)d_in[4];
  const float* lin_w = (const float*)d_in[5];
  const float* lin_b = (const float*)d_in[6];

  float* out   = (float*)d_out;        // [1,B,H] = 16384 floats
  float* w_out = out + B_ * H_;        // [S,B]   = 262144 floats

  float* ws     = (float*)d_ws;
  float* dW     = ws;
  float* pc     = ws + 16384;
  float* scores = ws + 16448;

  k1_prep<<<B_, 256, 0, stream>>>(d, W_a, W_p, v_p, dW, pc);
  k2_scores<<<dim3(B_, S_ / 64), 256, 0, stream>>>(e, dW, scores);
  kF<<<B_, 256, 0, stream>>>(scores, pc, e, d, lin_w, lin_b, out, w_out);
}